// Round 8
// baseline (124.275 us; speedup 1.0000x reference)
//
#include <hip/hip_runtime.h>

// CloudRasterizerOversample — R8: fused binning, occupancy-forced.
// History: R1 global fp32 atomics = 171us (23 G/s scattered-atomic wall).
// R6 fused single-pass scatter+accum = ~43us ours + ~73us fixed harness
// restore/poison floor -> 116 total. R7 (barrier/search removal) NEUTRAL ->
// chunk loop not serial-bound; hypothesis: 1024-thr blocks at >64 VGPR =
// 1 block/CU resident -> serial 2-chunk tail. R8: __launch_bounds__(1024,8)
// (64-VGPR cap -> 2 blocks/CU), PPT 4->2 (less live state, no spills),
// CHUNK 2048 (977 blocks, dynamic balance), LDS ~48KB (fits x2).

#define N_PIX_LO 128
#define NBKT 1024            // 64 v-slices x 16 y-bands (8 rows)
#define CAPB 4096            // record capacity per bucket (mean 2248, ~39sig)
#define TPB  1024            // threads per scatter block
#define PPT  2               // points per thread (one vf2 per input array)
#define CHUNK (TPB * PPT)    // 2048 points per block
#define STAGE 3584           // staged records/chunk (mean 2357, ~22sig)
#define TILE_FLOATS 1024     // accum band tile: 8 x 128

typedef unsigned int u32;
typedef unsigned short u16;
typedef unsigned long long u64;
typedef float vf2 __attribute__((ext_vector_type(2)));
typedef float vf4 __attribute__((ext_vector_type(4)));

// Exact reference binning (fp32 IEEE divide; must match np):
// FOV_HALF_HI=6.3875, PIX_HI=0.025, VEL0_HI=-404.6875, DV_HI=3.125
__device__ __forceinline__ bool decode_geom(float vra, float vde, float vve,
    int& cx, int& cy, int& cv, bool& bx, bool& by, bool& bv,
    float& fx, float& fy, float& fv)
{
    float gx = (vra + 6.3875f)   / 0.025f;
    float gy = (vde + 6.3875f)   / 0.025f;
    float gv = (vve + 404.6875f) / 3.125f;
    float fxf = floorf(gx), fyf = floorf(gy), fvf = floorf(gv);
    int ix0 = (int)fxf, iy0 = (int)fyf, iv0 = (int)fvf;
    fx = gx - fxf; fy = gy - fyf; fv = gv - fvf;
    if (ix0 < 0 || ix0 >= 511 || iy0 < 0 || iy0 >= 511 || iv0 < 0 || iv0 >= 255)
        return false;
    cx = ix0 >> 2; cy = iy0 >> 2; cv = iv0 >> 2;
    bx = (ix0 & 3) == 3; by = (iy0 & 3) == 3; bv = (iv0 & 3) == 3;
    return true;
}

__device__ __forceinline__ u64 mk_rec(u32 meta, float w)
{
    return (u64)meta | ((u64)__float_as_uint(w) << 32);
}

// Per-point packed state held in registers between phases:
//  pm: fxq[0:10) fyq[10:20) cx[20:27) bx[30]
//  pa: q0[0:10) cyl[10:13) ys[13] bv[14] valid[15] fvq[16:26) by[26]
__global__ __launch_bounds__(TPB, 8) void k_scatter_fused(
    const float* __restrict__ ra, const float* __restrict__ de,
    const float* __restrict__ vel, const float* __restrict__ flux,
    u32* __restrict__ gcur, u64* __restrict__ recs, int M)
{
    __shared__ u32 hist[NBKT];        // histogram, then stage cursor
    __shared__ u32 sbase[NBKT + 1];   // exclusive stage offsets (+ total)
    __shared__ u32 gofs[NBKT];        // gbase[b] - sbase[b] (u32 wrap exact)
    __shared__ u32 wsum[16];          // per-wave scan partials
    __shared__ u16 sbkt[STAGE];       // bucket id of each staged record
    __shared__ u64 stage[STAGE];      // bucket-grouped staged records
    int tid = threadIdx.x;
    int lane = tid & 63, wid = tid >> 6;

    hist[tid] = 0;                    // NBKT == TPB
    __syncthreads();

    int base = blockIdx.x * CHUNK;
    u32 pm[PPT], pa[PPT];
    float pf[PPT];

    // ---- phase A: load + decode once, count into LDS hist ----
    float rr[PPT], dd[PPT], vv[PPT], ff[PPT];
    if (base + 2 * tid + 1 < M) {
        int vi = (base >> 1) + tid;
        vf2 r2 = __builtin_nontemporal_load((const vf2*)ra + vi);
        vf2 d2 = __builtin_nontemporal_load((const vf2*)de + vi);
        vf2 v2 = __builtin_nontemporal_load((const vf2*)vel + vi);
        vf2 f2 = __builtin_nontemporal_load((const vf2*)flux + vi);
        rr[0]=r2.x; rr[1]=r2.y; dd[0]=d2.x; dd[1]=d2.y;
        vv[0]=v2.x; vv[1]=v2.y; ff[0]=f2.x; ff[1]=f2.y;
    } else {
        #pragma unroll
        for (int k = 0; k < PPT; ++k) {
            int p = base + 2 * tid + k;
            bool ok = p < M;
            rr[k] = ok ? ra[p] : 1e9f;   // 1e9 -> invalid in decode
            dd[k] = ok ? de[p] : 1e9f;
            vv[k] = ok ? vel[p] : 1e9f;
            ff[k] = ok ? flux[p] : 0.f;
        }
    }
    #pragma unroll
    for (int k = 0; k < PPT; ++k) {
        pa[k] = 0;
        int cx, cy, cv; bool bx, by, bv; float fx, fy, fv;
        if (decode_geom(rr[k], dd[k], vv[k], cx, cy, cv, bx, by, bv, fx, fy, fv)) {
            int band = cy >> 3, cyl = cy & 7;
            u32 q0 = (u32)((cv << 4) + band);
            bool ys = by && (cyl == 7);
            u32 fxq = (u32)(fx * 1023.f + 0.5f);
            u32 fyq = (u32)(fy * 1023.f + 0.5f);
            u32 fvq = (u32)(fv * 1023.f + 0.5f);
            pm[k] = fxq | (fyq << 10) | ((u32)cx << 20) | (bx ? (1u << 30) : 0u);
            pa[k] = q0 | ((u32)cyl << 10) | (ys ? (1u << 13) : 0u)
                  | (bv ? (1u << 14) : 0u) | (1u << 15) | (fvq << 16)
                  | (by ? (1u << 26) : 0u);
            pf[k] = ff[k] * 0.015625f;       // /64 mean-pool folded in
            atomicAdd(&hist[q0], 1u);
            if (ys) atomicAdd(&hist[q0 + 1], 1u);
            if (bv) {
                atomicAdd(&hist[q0 + 16], 1u);
                if (ys) atomicAdd(&hist[q0 + 17], 1u);
            }
        }
    }
    __syncthreads();

    // ---- phase B: wave-shuffle scan + 1 global atomic per bucket ----
    u32 c = hist[tid];
    u32 incl = c;
    #pragma unroll
    for (int off = 1; off < 64; off <<= 1) {
        u32 x = (u32)__shfl_up((int)incl, off, 64);
        if (lane >= off) incl += x;
    }
    if (lane == 63) wsum[wid] = incl;
    __syncthreads();
    if (tid < 16) {
        u32 v = wsum[tid];
        u32 i2 = v;
        #pragma unroll
        for (int off = 1; off < 16; off <<= 1) {
            u32 x = (u32)__shfl_up((int)i2, off, 64);
            if (tid >= off) i2 += x;
        }
        wsum[tid] = i2 - v;                // exclusive wave offset
    }
    __syncthreads();
    u32 excl = wsum[wid] + incl - c;       // exclusive stage offset
    sbase[tid] = excl;
    hist[tid] = excl;                      // reuse as stage cursor
    u32 gb = c ? atomicAdd(&gcur[tid], c) : 0u;
    gofs[tid] = gb - excl;                 // u32 wrap: gb + (s - excl)
    if (tid == NBKT - 1) sbase[NBKT] = excl + c;
    __syncthreads();
    u32 total = sbase[NBKT];

    // ---- phase C: place records bucket-grouped into LDS stage ----
    #pragma unroll
    for (int k = 0; k < PPT; ++k) {
        u32 a = pa[k];
        if (!(a & (1u << 15))) continue;
        u32 q0  = a & 1023u;
        u32 cyl = (a >> 10) & 7u;
        bool ys = a & (1u << 13);
        bool bv = a & (1u << 14);
        bool by = a & (1u << 26);
        float fv = (float)((a >> 16) & 1023u) * (1.f / 1023.f);
        u32 mb = pm[k];
        float fy = (float)((mb >> 10) & 1023u) * (1.f / 1023.f);
        float f = pf[k];
        float wy0 = ys ? (1.f - fy) : 1.f;
        u32 meta0 = mb | (cyl << 27) | ((by && !ys) ? (1u << 31) : 0u);
        float wv0 = bv ? (1.f - fv) : 1.f;
        float w0 = f * wv0;
        u32 s = atomicAdd(&hist[q0], 1u);
        if (s < STAGE) { stage[s] = mk_rec(meta0, w0 * wy0); sbkt[s] = (u16)q0; }
        if (ys) {
            u32 s2 = atomicAdd(&hist[q0 + 1], 1u);
            if (s2 < STAGE) { stage[s2] = mk_rec(mb, w0 * fy); sbkt[s2] = (u16)(q0 + 1); }
        }
        if (bv) {
            float w1 = f * fv;
            u32 s3 = atomicAdd(&hist[q0 + 16], 1u);
            if (s3 < STAGE) { stage[s3] = mk_rec(meta0, w1 * wy0); sbkt[s3] = (u16)(q0 + 16); }
            if (ys) {
                u32 s4 = atomicAdd(&hist[q0 + 17], 1u);
                if (s4 < STAGE) { stage[s4] = mk_rec(mb, w1 * fy); sbkt[s4] = (u16)(q0 + 17); }
            }
        }
    }
    __syncthreads();

    // ---- phase D: grouped coalesced copy-out (direct bucket lookup) ----
    u32 lim = total < STAGE ? total : STAGE;
    for (u32 s = tid; s < lim; s += TPB) {
        u32 b = sbkt[s];
        u32 slot = gofs[b] + s;            // == gbase[b] + (s - sbase[b])
        if (slot < CAPB)
            recs[(size_t)b * CAPB + slot] = stage[s];
    }
}

// grid = NBKT; block q accumulates its 8x128 band in a 4KB LDS tile.
__global__ __launch_bounds__(256) void k_accum(
    const u32* __restrict__ gcur, const u64* __restrict__ recs,
    float* __restrict__ out)
{
    __shared__ float tile[TILE_FLOATS];
    int q = blockIdx.x, t = threadIdx.x;
    #pragma unroll
    for (int i = t; i < TILE_FLOATS; i += 256) tile[i] = 0.f;
    u32 n = gcur[q];
    if (n > CAPB) n = CAPB;
    const u64* rp = recs + (size_t)q * CAPB;
    __syncthreads();

    for (u32 p = t; p < n; p += 256) {
        u64 rr = rp[p];
        u32 m = (u32)rr;
        float w = __uint_as_float((u32)(rr >> 32));
        float fx = (float)(m & 1023u)         * (1.f / 1023.f);
        float fy = (float)((m >> 10) & 1023u) * (1.f / 1023.f);
        int cx  = (m >> 20) & 127;
        int cyl = (m >> 27) & 7;
        bool bx = (m >> 30) & 1u;
        bool by = (m >> 31) != 0u;
        float wx0 = bx ? (1.f - fx) : 1.f;
        float wy0 = by ? (1.f - fy) : 1.f;
        int idx = cyl * N_PIX_LO + cx;
        atomicAdd(&tile[idx], w * wx0 * wy0);
        if (bx) atomicAdd(&tile[idx + 1], w * fx * wy0);
        if (by) {
            atomicAdd(&tile[idx + N_PIX_LO], w * wx0 * fy);
            if (bx) atomicAdd(&tile[idx + N_PIX_LO + 1], w * fx * fy);
        }
    }
    __syncthreads();

    vf4* o = (vf4*)(out + (size_t)q * TILE_FLOATS);
    const vf4* t4 = (const vf4*)tile;
    #pragma unroll
    for (int i = t; i < TILE_FLOATS / 4; i += 256)
        __builtin_nontemporal_store(t4[i], o + i);
}

// ---- fallback: direct global-atomic splat (R1) ----
__global__ __launch_bounds__(256) void k_fallback(
    const float* __restrict__ ra, const float* __restrict__ de,
    const float* __restrict__ vel, const float* __restrict__ flux,
    float* __restrict__ out, int M)
{
    int i = blockIdx.x * blockDim.x + threadIdx.x;
    if (i >= M) return;
    int cx, cy, cv; bool bx, by, bv; float fx, fy, fv;
    if (!decode_geom(ra[i], de[i], vel[i], cx, cy, cv, bx, by, bv, fx, fy, fv)) return;
    float f = flux[i] * 0.015625f;
    float wx0 = bx ? (1.f - fx) : 1.f, wy0 = by ? (1.f - fy) : 1.f, wv0 = bv ? (1.f - fv) : 1.f;
    int nx = bx ? 2 : 1, ny = by ? 2 : 1, nv = bv ? 2 : 1;
    for (int a = 0; a < nv; ++a) {
        float wva = a ? fv : wv0;
        for (int b = 0; b < ny; ++b) {
            float wab = f * wva * (b ? fy : wy0);
            int basei = (((cv + a) * N_PIX_LO) + (cy + b)) * N_PIX_LO + cx;
            for (int c = 0; c < nx; ++c)
                atomicAdd(&out[basei + c], wab * (c ? fx : wx0));
        }
    }
}

extern "C" void kernel_launch(void* const* d_in, const int* in_sizes, int n_in,
                              void* d_out, int out_size, void* d_ws, size_t ws_size,
                              hipStream_t stream) {
    const float* ra   = (const float*)d_in[0];
    const float* de   = (const float*)d_in[1];
    const float* vel  = (const float*)d_in[2];
    const float* flux = (const float*)d_in[3];
    float* out = (float*)d_out;
    int M = in_sizes[0];

    // ws: gcur (4KB) | recs = NBKT*CAPB*8 = 32 MB
    const size_t recs_off = 4096;
    const size_t need = recs_off + (size_t)NBKT * CAPB * sizeof(u64);

    if (ws_size >= need) {
        u32* gcur = (u32*)d_ws;
        u64* recs = (u64*)((char*)d_ws + recs_off);
        int nchunks = (M + CHUNK - 1) / CHUNK;
        (void)hipMemsetAsync(gcur, 0, NBKT * sizeof(u32), stream);
        k_scatter_fused<<<nchunks, TPB, 0, stream>>>(ra, de, vel, flux,
                                                     gcur, recs, M);
        k_accum<<<NBKT, 256, 0, stream>>>(gcur, recs, out);
    } else {
        (void)hipMemsetAsync(out, 0, (size_t)out_size * sizeof(float), stream);
        int grid = (M + 255) / 256;
        k_fallback<<<grid, 256, 0, stream>>>(ra, de, vel, flux, out, M);
    }
}

// Round 9
// 115.780 us; speedup vs baseline: 1.0734x; 1.0734x over previous
//
#include <hip/hip_runtime.h>

// CloudRasterizerOversample — R9: R7 pipeline + persistent-block prefetch +
// guarded reciprocal-multiply decode.
// History: R1 global fp32 atomics 171us (23 G/s scattered-atomic wall).
// R6/R7 fused bucket-scatter + LDS accum = 116us total (~45us ours on top of
// ~71us harness restore/poison floor). R7 barrier/search removal NEUTRAL;
// R8 occupancy-forcing REGRESSED (124us) -> not residency-bound. Model:
// exposed latency (HBM load + IEEE div chains + LDS atomic chains, 16
// waves/CU). R9: prefetch next chunk's vf4 loads before current phases;
// replace 3 IEEE divides with multiplies (+ exact-divide guard near the
// discontinuous validity edges 511/255; 0-edges are sign-exact).

#define N_PIX_LO 128
#define NBKT 1024            // 64 v-slices x 16 y-bands (8 rows)
#define CAPB 4096            // record capacity per bucket (mean 2248, ~39sig)
#define TPB  1024            // threads per scatter block
#define PPT  4               // points per thread (one vf4 per input array)
#define CHUNK (TPB * PPT)    // 4096 points per chunk
#define PGRID 256            // persistent blocks (1 per CU)
#define STAGE 6400           // staged records/chunk (mean 4694, ~32sig)
#define TILE_FLOATS 1024     // accum band tile: 8 x 128

typedef unsigned int u32;
typedef unsigned short u16;
typedef unsigned long long u64;
typedef float vf4 __attribute__((ext_vector_type(4)));
typedef u64 v2u64 __attribute__((ext_vector_type(2)));

constexpr float RCP_PIX = 1.0f / 0.025f;   // correctly-rounded fp32 (== 40.0f)
constexpr float RCP_DV  = 1.0f / 3.125f;   // correctly-rounded fp32 (0.32 - 1ulp)

// Reference binning: FOV_HALF_HI=6.3875, PIX_HI=0.025, VEL0_HI=-404.6875,
// DV_HI=3.125 (fp32). Multiply-by-reciprocal differs from IEEE divide by
// <=1 ulp; interior bin flips are weight-continuous (harmless), and the 0
// edges are sign-exact under multiply. Only the 511/255 validity edges are
// discontinuous -> re-divide inside a 1e-3 window (~1e-6 of points).
__device__ __forceinline__ bool decode_geom(float vra, float vde, float vve,
    int& cx, int& cy, int& cv, bool& bx, bool& by, bool& bv,
    float& fx, float& fy, float& fv)
{
    float sx = vra + 6.3875f;
    float sy = vde + 6.3875f;
    float sv = vve + 404.6875f;
    float gx = sx * RCP_PIX;
    float gy = sy * RCP_PIX;
    float gv = sv * RCP_DV;
    if (__builtin_expect(fabsf(gx - 511.f) < 1e-3f, 0)) gx = sx / 0.025f;
    if (__builtin_expect(fabsf(gy - 511.f) < 1e-3f, 0)) gy = sy / 0.025f;
    if (__builtin_expect(fabsf(gv - 255.f) < 1e-3f, 0)) gv = sv / 3.125f;
    float fxf = floorf(gx), fyf = floorf(gy), fvf = floorf(gv);
    int ix0 = (int)fxf, iy0 = (int)fyf, iv0 = (int)fvf;
    fx = gx - fxf; fy = gy - fyf; fv = gv - fvf;
    if (ix0 < 0 || ix0 >= 511 || iy0 < 0 || iy0 >= 511 || iv0 < 0 || iv0 >= 255)
        return false;
    cx = ix0 >> 2; cy = iy0 >> 2; cv = iv0 >> 2;
    bx = (ix0 & 3) == 3; by = (iy0 & 3) == 3; bv = (iv0 & 3) == 3;
    return true;
}

__device__ __forceinline__ u64 mk_rec(u32 meta, float w)
{
    return (u64)meta | ((u64)__float_as_uint(w) << 32);
}

// Per-point packed state held in registers between phases:
//  pm: fxq[0:10) fyq[10:20) cx[20:27) bx[30]
//  pa: q0[0:10) cyl[10:13) ys[13] bv[14] valid[15] fvq[16:26) by[26]
__global__ __launch_bounds__(TPB) void k_scatter_fused(
    const float* __restrict__ ra, const float* __restrict__ de,
    const float* __restrict__ vel, const float* __restrict__ flux,
    u32* __restrict__ gcur, u64* __restrict__ recs, int M, int nchunks)
{
    __shared__ u32 hist[NBKT];        // histogram, then stage cursor
    __shared__ u32 sbase[NBKT + 1];   // exclusive stage offsets (+ total)
    __shared__ u32 gofs[NBKT];        // gbase[b] - sbase[b] (u32 wrap exact)
    __shared__ u32 wsum[16];          // per-wave scan partials
    __shared__ u16 sbkt[STAGE];       // bucket id of each staged record
    __shared__ u64 stage[STAGE];      // bucket-grouped staged records
    int tid = threadIdx.x;
    int lane = tid & 63, wid = tid >> 6;

    int chunk = blockIdx.x;
    vf4 cr, cd, cw, cf;               // current chunk's quad (prefetched)
    bool cvec = false;
    if (chunk < nchunks) {
        int base = chunk * CHUNK;
        cvec = (base + 4 * tid + 3) < M;
        if (cvec) {
            int vi = (base >> 2) + tid;
            cr = __builtin_nontemporal_load((const vf4*)ra + vi);
            cd = __builtin_nontemporal_load((const vf4*)de + vi);
            cw = __builtin_nontemporal_load((const vf4*)vel + vi);
            cf = __builtin_nontemporal_load((const vf4*)flux + vi);
        }
    }

    for (; chunk < nchunks; chunk += PGRID) {
        // ---- prefetch next chunk's quad (in flight during phases A-D) ----
        int nxt = chunk + PGRID;
        vf4 nr, nd, nw, nf;
        bool nvec = false;
        if (nxt < nchunks) {
            int nb = nxt * CHUNK;
            nvec = (nb + 4 * tid + 3) < M;
            if (nvec) {
                int vi = (nb >> 2) + tid;
                nr = __builtin_nontemporal_load((const vf4*)ra + vi);
                nd = __builtin_nontemporal_load((const vf4*)de + vi);
                nw = __builtin_nontemporal_load((const vf4*)vel + vi);
                nf = __builtin_nontemporal_load((const vf4*)flux + vi);
            }
        }

        hist[tid] = 0;                 // NBKT == TPB
        __syncthreads();

        int base = chunk * CHUNK;
        u32 pm[PPT], pa[PPT];
        float pf[PPT];
        float rr[PPT], dd[PPT], vv[PPT], ff[PPT];

        // ---- phase A: unpack + decode once, count into LDS hist ----
        if (cvec) {
            rr[0]=cr.x; rr[1]=cr.y; rr[2]=cr.z; rr[3]=cr.w;
            dd[0]=cd.x; dd[1]=cd.y; dd[2]=cd.z; dd[3]=cd.w;
            vv[0]=cw.x; vv[1]=cw.y; vv[2]=cw.z; vv[3]=cw.w;
            ff[0]=cf.x; ff[1]=cf.y; ff[2]=cf.z; ff[3]=cf.w;
        } else {
            #pragma unroll
            for (int k = 0; k < PPT; ++k) {
                int p = base + 4 * tid + k;
                bool ok = p < M;
                rr[k] = ok ? ra[p] : 1e9f;   // 1e9 -> invalid in decode
                dd[k] = ok ? de[p] : 1e9f;
                vv[k] = ok ? vel[p] : 1e9f;
                ff[k] = ok ? flux[p] : 0.f;
            }
        }
        #pragma unroll
        for (int k = 0; k < PPT; ++k) {
            pa[k] = 0;
            int cx, cy, cvv; bool bx, by, bv; float fx, fy, fv;
            if (decode_geom(rr[k], dd[k], vv[k], cx, cy, cvv, bx, by, bv, fx, fy, fv)) {
                int band = cy >> 3, cyl = cy & 7;
                u32 q0 = (u32)((cvv << 4) + band);
                bool ys = by && (cyl == 7);
                u32 fxq = (u32)(fx * 1023.f + 0.5f);
                u32 fyq = (u32)(fy * 1023.f + 0.5f);
                u32 fvq = (u32)(fv * 1023.f + 0.5f);
                pm[k] = fxq | (fyq << 10) | ((u32)cx << 20) | (bx ? (1u << 30) : 0u);
                pa[k] = q0 | ((u32)cyl << 10) | (ys ? (1u << 13) : 0u)
                      | (bv ? (1u << 14) : 0u) | (1u << 15) | (fvq << 16)
                      | (by ? (1u << 26) : 0u);
                pf[k] = ff[k] * 0.015625f;   // /64 mean-pool folded in
                atomicAdd(&hist[q0], 1u);
                if (ys) atomicAdd(&hist[q0 + 1], 1u);
                if (bv) {
                    atomicAdd(&hist[q0 + 16], 1u);
                    if (ys) atomicAdd(&hist[q0 + 17], 1u);
                }
            }
        }
        __syncthreads();

        // ---- phase B: wave-shuffle scan + 1 global atomic per bucket ----
        u32 c = hist[tid];
        u32 incl = c;
        #pragma unroll
        for (int off = 1; off < 64; off <<= 1) {
            u32 x = (u32)__shfl_up((int)incl, off, 64);
            if (lane >= off) incl += x;
        }
        if (lane == 63) wsum[wid] = incl;
        __syncthreads();
        if (tid < 16) {
            u32 v = wsum[tid];
            u32 i2 = v;
            #pragma unroll
            for (int off = 1; off < 16; off <<= 1) {
                u32 x = (u32)__shfl_up((int)i2, off, 64);
                if (tid >= off) i2 += x;
            }
            wsum[tid] = i2 - v;            // exclusive wave offset
        }
        __syncthreads();
        u32 excl = wsum[wid] + incl - c;   // exclusive stage offset
        sbase[tid] = excl;
        hist[tid] = excl;                  // reuse as stage cursor
        u32 gb = c ? atomicAdd(&gcur[tid], c) : 0u;
        gofs[tid] = gb - excl;             // u32 wrap: gb + (s - excl)
        if (tid == NBKT - 1) sbase[NBKT] = excl + c;
        __syncthreads();
        u32 total = sbase[NBKT];

        // ---- phase C: place records bucket-grouped into LDS stage ----
        #pragma unroll
        for (int k = 0; k < PPT; ++k) {
            u32 a = pa[k];
            if (!(a & (1u << 15))) continue;
            u32 q0  = a & 1023u;
            u32 cyl = (a >> 10) & 7u;
            bool ys = a & (1u << 13);
            bool bv = a & (1u << 14);
            bool by = a & (1u << 26);
            float fv = (float)((a >> 16) & 1023u) * (1.f / 1023.f);
            u32 mb = pm[k];
            float fy = (float)((mb >> 10) & 1023u) * (1.f / 1023.f);
            float f = pf[k];
            float wy0 = ys ? (1.f - fy) : 1.f;
            u32 meta0 = mb | (cyl << 27) | ((by && !ys) ? (1u << 31) : 0u);
            float wv0 = bv ? (1.f - fv) : 1.f;
            float w0 = f * wv0;
            u32 s = atomicAdd(&hist[q0], 1u);
            if (s < STAGE) { stage[s] = mk_rec(meta0, w0 * wy0); sbkt[s] = (u16)q0; }
            if (ys) {
                u32 s2 = atomicAdd(&hist[q0 + 1], 1u);
                if (s2 < STAGE) { stage[s2] = mk_rec(mb, w0 * fy); sbkt[s2] = (u16)(q0 + 1); }
            }
            if (bv) {
                float w1 = f * fv;
                u32 s3 = atomicAdd(&hist[q0 + 16], 1u);
                if (s3 < STAGE) { stage[s3] = mk_rec(meta0, w1 * wy0); sbkt[s3] = (u16)(q0 + 16); }
                if (ys) {
                    u32 s4 = atomicAdd(&hist[q0 + 17], 1u);
                    if (s4 < STAGE) { stage[s4] = mk_rec(mb, w1 * fy); sbkt[s4] = (u16)(q0 + 17); }
                }
            }
        }
        __syncthreads();

        // ---- phase D: grouped coalesced copy-out (direct bucket lookup) ----
        u32 lim = total < STAGE ? total : STAGE;
        for (u32 s = tid; s < lim; s += TPB) {
            u32 b = sbkt[s];
            u32 slot = gofs[b] + s;        // == gbase[b] + (s - sbase[b])
            if (slot < CAPB)
                recs[(size_t)b * CAPB + slot] = stage[s];
        }
        __syncthreads();

        cr = nr; cd = nd; cw = nw; cf = nf; cvec = nvec;
    }
}

__device__ __forceinline__ void accum_rec(u64 rr, float* tile)
{
    u32 m = (u32)rr;
    float w = __uint_as_float((u32)(rr >> 32));
    float fx = (float)(m & 1023u)         * (1.f / 1023.f);
    float fy = (float)((m >> 10) & 1023u) * (1.f / 1023.f);
    int cx  = (m >> 20) & 127;
    int cyl = (m >> 27) & 7;
    bool bx = (m >> 30) & 1u;
    bool by = (m >> 31) != 0u;
    float wx0 = bx ? (1.f - fx) : 1.f;
    float wy0 = by ? (1.f - fy) : 1.f;
    int idx = cyl * N_PIX_LO + cx;
    atomicAdd(&tile[idx], w * wx0 * wy0);
    if (bx) atomicAdd(&tile[idx + 1], w * fx * wy0);
    if (by) {
        atomicAdd(&tile[idx + N_PIX_LO], w * wx0 * fy);
        if (bx) atomicAdd(&tile[idx + N_PIX_LO + 1], w * fx * fy);
    }
}

// grid = NBKT; block q accumulates its 8x128 band in a 4KB LDS tile.
__global__ __launch_bounds__(256) void k_accum(
    const u32* __restrict__ gcur, const u64* __restrict__ recs,
    float* __restrict__ out)
{
    __shared__ float tile[TILE_FLOATS];
    int q = blockIdx.x, t = threadIdx.x;
    #pragma unroll
    for (int i = t; i < TILE_FLOATS; i += 256) tile[i] = 0.f;
    u32 n = gcur[q];
    if (n > CAPB) n = CAPB;
    const u64* rp = recs + (size_t)q * CAPB;   // 32 KB-aligned
    const v2u64* rp2 = (const v2u64*)rp;
    u32 n2 = n >> 1;
    __syncthreads();

    for (u32 p = t; p < n2; p += 256) {
        v2u64 rr2 = rp2[p];
        accum_rec(rr2.x, tile);
        accum_rec(rr2.y, tile);
    }
    if ((n & 1u) && t == 0) accum_rec(rp[n - 1], tile);
    __syncthreads();

    vf4* o = (vf4*)(out + (size_t)q * TILE_FLOATS);
    const vf4* t4 = (const vf4*)tile;
    #pragma unroll
    for (int i = t; i < TILE_FLOATS / 4; i += 256)
        __builtin_nontemporal_store(t4[i], o + i);
}

// ---- fallback: direct global-atomic splat (R1) ----
__global__ __launch_bounds__(256) void k_fallback(
    const float* __restrict__ ra, const float* __restrict__ de,
    const float* __restrict__ vel, const float* __restrict__ flux,
    float* __restrict__ out, int M)
{
    int i = blockIdx.x * blockDim.x + threadIdx.x;
    if (i >= M) return;
    int cx, cy, cv; bool bx, by, bv; float fx, fy, fv;
    if (!decode_geom(ra[i], de[i], vel[i], cx, cy, cv, bx, by, bv, fx, fy, fv)) return;
    float f = flux[i] * 0.015625f;
    float wx0 = bx ? (1.f - fx) : 1.f, wy0 = by ? (1.f - fy) : 1.f, wv0 = bv ? (1.f - fv) : 1.f;
    int nx = bx ? 2 : 1, ny = by ? 2 : 1, nv = bv ? 2 : 1;
    for (int a = 0; a < nv; ++a) {
        float wva = a ? fv : wv0;
        for (int b = 0; b < ny; ++b) {
            float wab = f * wva * (b ? fy : wy0);
            int basei = (((cv + a) * N_PIX_LO) + (cy + b)) * N_PIX_LO + cx;
            for (int c = 0; c < nx; ++c)
                atomicAdd(&out[basei + c], wab * (c ? fx : wx0));
        }
    }
}

extern "C" void kernel_launch(void* const* d_in, const int* in_sizes, int n_in,
                              void* d_out, int out_size, void* d_ws, size_t ws_size,
                              hipStream_t stream) {
    const float* ra   = (const float*)d_in[0];
    const float* de   = (const float*)d_in[1];
    const float* vel  = (const float*)d_in[2];
    const float* flux = (const float*)d_in[3];
    float* out = (float*)d_out;
    int M = in_sizes[0];

    // ws: gcur (4KB) | recs = NBKT*CAPB*8 = 32 MB
    const size_t recs_off = 4096;
    const size_t need = recs_off + (size_t)NBKT * CAPB * sizeof(u64);

    if (ws_size >= need) {
        u32* gcur = (u32*)d_ws;
        u64* recs = (u64*)((char*)d_ws + recs_off);
        int nchunks = (M + CHUNK - 1) / CHUNK;
        int grid = nchunks < PGRID ? nchunks : PGRID;
        (void)hipMemsetAsync(gcur, 0, NBKT * sizeof(u32), stream);
        k_scatter_fused<<<grid, TPB, 0, stream>>>(ra, de, vel, flux,
                                                  gcur, recs, M, nchunks);
        k_accum<<<NBKT, 256, 0, stream>>>(gcur, recs, out);
    } else {
        (void)hipMemsetAsync(out, 0, (size_t)out_size * sizeof(float), stream);
        int grid = (M + 255) / 256;
        k_fallback<<<grid, 256, 0, stream>>>(ra, de, vel, flux, out, M);
    }
}